// Round 2
// baseline (288.508 us; speedup 1.0000x reference)
//
#include <hip/hip_runtime.h>
#include <hip/hip_bf16.h>

// N=4, C=256, H=W=64 -> HW=4096, E=128, 3E=384.
// Raw-reshape insight: qkv flat [n][o][hw] buffer IS [n][p][384] with
// q = flat[p*384+0..127], k = +128, v = +256.  attn flat [n][i*128+d] IS [n][e][hw].

typedef short bfrag __attribute__((ext_vector_type(8)));   // 8 bf16 (4 VGPRs)
typedef float ffrag __attribute__((ext_vector_type(4)));   // 4 fp32 acc
#define MFMA(a,b,c) __builtin_amdgcn_mfma_f32_16x16x32_bf16((a),(b),(c),0,0,0)

__device__ __forceinline__ unsigned short f2bf(float f){
  union { float f; unsigned u; } v; v.f = f;
  unsigned r = v.u + 0x7fffu + ((v.u >> 16) & 1u);   // RNE
  return (unsigned short)(r >> 16);
}

// ---------------- K0: cast weights to bf16 ----------------
__global__ __launch_bounds__(256) void k_wcast(const float* __restrict__ Wq, const float* __restrict__ Wo,
                                               unsigned short* __restrict__ Wqb, unsigned short* __restrict__ Wob){
  int i = blockIdx.x*256 + threadIdx.x;
  if (i < 384*256) Wqb[i] = f2bf(Wq[i]);
  if (i < 256*128) Wob[i] = f2bf(Wo[i]);
}

// ---------------- K1: QKV projection ----------------
// qkv[n][o][hw] = sum_c Wq[o][c]*x[n][c][hw] + bq[o], written as bf16 (flat layout).
__global__ __launch_bounds__(256) void k_qkv(const float* __restrict__ x, const unsigned short* __restrict__ Wqb,
                                             const float* __restrict__ bq, unsigned short* __restrict__ qkv){
  constexpr int LD = 136;
  __shared__ __align__(16) unsigned short As[64*LD];   // W tile [o][c-half]
  __shared__ __align__(16) unsigned short Bs[64*LD];   // X^T tile [hw][c-half]
  const int o0 = blockIdx.x*64, h0 = blockIdx.y*64, n = blockIdx.z;
  const int t = threadIdx.x, w = t>>6, lane = t&63, lr = lane&15, q4 = lane>>4;
  ffrag acc[4] = {};
  for (int kh = 0; kh < 2; ++kh) {
    __syncthreads();
    #pragma unroll
    for (int r=0;r<4;++r){                       // 64 o x 16 segs of 8
      int pi = t + 256*r; int o = pi>>4, seg = pi&15;
      *(uint4*)&As[o*LD + seg*8] = *(const uint4*)(Wqb + (o0+o)*256 + kh*128 + seg*8);
    }
    #pragma unroll
    for (int r=0;r<32;++r){                      // transpose-stage x: 128 c x 64 hw
      int idx = t + 256*r; int cl = idx>>6, hl = idx&63;
      float v = x[(size_t)(n*256 + kh*128 + cl)*4096 + h0 + hl];
      Bs[hl*LD + cl] = f2bf(v);
    }
    __syncthreads();
    #pragma unroll
    for (int kk=0;kk<4;++kk){
      bfrag a = *(const bfrag*)&As[(w*16+lr)*LD + kk*32 + q4*8];
      #pragma unroll
      for (int tn=0;tn<4;++tn){
        bfrag b = *(const bfrag*)&Bs[(tn*16+lr)*LD + kk*32 + q4*8];
        acc[tn] = MFMA(a,b,acc[tn]);
      }
    }
  }
  size_t base = (size_t)n*384*4096;
  #pragma unroll
  for (int tn=0;tn<4;++tn)
    #pragma unroll
    for (int r=0;r<4;++r){
      int o  = o0 + w*16 + q4*4 + r;
      int hw = h0 + tn*16 + lr;
      qkv[base + (size_t)o*4096 + hw] = f2bf(acc[tn][r] + bq[o]);
    }
}

// ---------------- K2: global V transpose: vt[n][d][p] = v[n][p][d] ----------------
__global__ __launch_bounds__(256) void k_vtrans(const unsigned short* __restrict__ qkv, unsigned short* __restrict__ vt){
  constexpr int LD = 136;
  __shared__ __align__(16) unsigned short T[64*LD];
  const int p0 = blockIdx.x*64, n = blockIdx.y;
  const int t = threadIdx.x;
  size_t base = (size_t)n*384*4096;
  #pragma unroll
  for (int r=0;r<4;++r){
    int pi = t + 256*r; int pl = pi>>4, seg = pi&15;
    *(uint4*)&T[pl*LD + seg*8] = *(const uint4*)(qkv + base + (size_t)(p0+pl)*384 + 256 + seg*8);
  }
  __syncthreads();
  unsigned* vt32 = (unsigned*)(vt + (size_t)n*128*4096);
  #pragma unroll
  for (int r=0;r<16;++r){
    int pi = t + 256*r;            // 4096 = 128 d x 32 p-pairs  (FIX: was 8 -> only half the p's)
    int d = pi>>5, k = pi&31;
    unsigned lo = T[(2*k)*LD + d];
    unsigned hi = T[(2*k+1)*LD + d];
    vt32[(size_t)d*2048 + (p0>>1) + k] = lo | (hi<<16);
  }
}

// ---------------- K3: column stats (softmax over i, per column j) ----------------
__global__ __launch_bounds__(256) void k_stats(const unsigned short* __restrict__ qkv,
                                               float* __restrict__ mp, float* __restrict__ zp){
  constexpr int LD = 136;
  __shared__ __align__(16) unsigned short Ks[64*LD];
  __shared__ __align__(16) unsigned short Qs[16*LD];
  const int j0 = blockIdx.x*64, ic = blockIdx.y, n = blockIdx.z;
  const int t = threadIdx.x, w = t>>6, lane = t&63, lr = lane&15, q4 = lane>>4;
  size_t base = (size_t)n*384*4096;
  #pragma unroll
  for (int r=0;r<4;++r){
    int pi = t + 256*r; int jl = pi>>4, seg = pi&15;
    *(uint4*)&Ks[jl*LD + seg*8] = *(const uint4*)(qkv + base + (size_t)(j0+jl)*384 + 128 + seg*8);
  }
  float m = -3.0e38f, Z = 0.f;
  const float inv64 = 0.015625f;
  for (int ii=0; ii<64; ++ii){
    int i0 = (ic<<10) + ii*16;
    __syncthreads();
    { int il = t>>4, seg = t&15;
      *(uint4*)&Qs[il*LD + seg*8] = *(const uint4*)(qkv + base + (size_t)(i0+il)*384 + seg*8); }
    __syncthreads();
    ffrag s = {};
    #pragma unroll
    for (int kk=0;kk<4;++kk){
      bfrag a = *(const bfrag*)&Qs[lr*LD + kk*32 + q4*8];               // A[m=i][k=d]
      bfrag b = *(const bfrag*)&Ks[(w*16+lr)*LD + kk*32 + q4*8];        // B[k=d][n=j]
      s = MFMA(a,b,s);
    }
    float s0=s[0]*inv64, s1=s[1]*inv64, s2=s[2]*inv64, s3=s[3]*inv64;
    float tm = fmaxf(fmaxf(s0,s1), fmaxf(s2,s3));
    tm = fmaxf(tm, __shfl_xor(tm, 16));
    tm = fmaxf(tm, __shfl_xor(tm, 32));
    float nm = fmaxf(m, tm);
    float se = __expf(s0-nm)+__expf(s1-nm)+__expf(s2-nm)+__expf(s3-nm);
    se += __shfl_xor(se, 16);
    se += __shfl_xor(se, 32);
    Z = Z*__expf(m-nm) + se;
    m = nm;
  }
  if (lane < 16){
    int idx = (((n<<2)+ic)<<12) + j0 + w*16 + lane;
    mp[idx] = m; zp[idx] = Z;
  }
}

// ---------------- K4: merge partial stats -> lse[n][j] = m + log Z ----------------
__global__ __launch_bounds__(256) void k_merge(const float* __restrict__ mp, const float* __restrict__ zp,
                                               float* __restrict__ lse){
  int idx = blockIdx.x*256 + threadIdx.x;   // n*4096 + j, 16384 total
  int n = idx>>12, j = idx&4095;
  float m = -3.0e38f, Z = 0.f;
  #pragma unroll
  for (int c=0;c<4;++c){
    int k = (((n<<2)+c)<<12) + j;
    float mc = mp[k], zc = zp[k];
    float nm = fmaxf(m, mc);
    Z = Z*__expf(m-nm) + zc*__expf(mc-nm);
    m = nm;
  }
  lse[idx] = m + __logf(Z);
}

// ---------------- K5: PV pass: out[i][d] = sum_j exp(s_ij - lse_j) * v[j][d] ----------------
__global__ __launch_bounds__(256) void k_attn(const unsigned short* __restrict__ qkv,
                                              const unsigned short* __restrict__ vtg_all,
                                              const float* __restrict__ lse,
                                              float* __restrict__ part){
  constexpr int LDK = 136, LDV = 56, LDP = 56;
  __shared__ __align__(16) unsigned short Ks[32*LDK];
  __shared__ __align__(16) unsigned short Vt[128*LDV];
  __shared__ __align__(16) unsigned short Pw[4][16*LDP];
  const int i0 = blockIdx.x*64, jh = blockIdx.y, n = blockIdx.z;
  const int t = threadIdx.x, w = t>>6, lane = t&63, lr = lane&15, q4 = lane>>4;
  size_t base = (size_t)n*384*4096;
  const unsigned short* vtg = vtg_all + (size_t)n*128*4096;
  const float* lsen = lse + (n<<12);
  bfrag qf[4];
  {
    const unsigned short* qrow = qkv + base + (size_t)(i0 + w*16 + lr)*384;
    #pragma unroll
    for (int kk=0;kk<4;++kk) qf[kk] = *(const bfrag*)(qrow + kk*32 + q4*8);
  }
  ffrag acc[8] = {};
  const float inv64 = 0.015625f;
  for (int j0 = jh*2048; j0 < jh*2048+2048; j0 += 32){
    __syncthreads();
    #pragma unroll
    for (int r=0;r<2;++r){                    // stage K rows j0..j0+31
      int pi = t + 256*r; int jl = pi>>4, seg = pi&15;
      *(uint4*)&Ks[jl*LDK + seg*8] = *(const uint4*)(qkv + base + (size_t)(j0+jl)*384 + 128 + seg*8);
    }
    #pragma unroll
    for (int r=0;r<2;++r){                    // stage Vt[128 d][32 j] (already transposed globally)
      int pi = t + 256*r; int d = pi>>2, seg = pi&3;
      *(uint4*)&Vt[d*LDV + seg*8] = *(const uint4*)(vtg + (size_t)d*4096 + j0 + seg*8);
    }
    __syncthreads();
    #pragma unroll
    for (int t16=0;t16<2;++t16){
      ffrag s = {};
      #pragma unroll
      for (int kk=0;kk<4;++kk){
        bfrag b = *(const bfrag*)&Ks[(t16*16+lr)*LDK + kk*32 + q4*8];
        s = MFMA(qf[kk], b, s);               // S[i][j] tile
      }
      float l = lsen[j0 + t16*16 + lr];
      #pragma unroll
      for (int r=0;r<4;++r){
        float p = __expf(s[r]*inv64 - l);
        Pw[w][(q4*4+r)*LDP + t16*16 + lr] = f2bf(p);   // wave-private
      }
    }
    // compiler-only fence: forbid reordering the vector read of Pw above the
    // scalar writes (HW DS ops are in-order per wave, so no s_waitcnt needed)
    asm volatile("" ::: "memory");
    bfrag a = *(const bfrag*)&Pw[w][lr*LDP + q4*8];    // A[m=i][k=j], k spans all 32 j
    #pragma unroll
    for (int dt=0;dt<8;++dt){
      bfrag b = *(const bfrag*)&Vt[(dt*16+lr)*LDV + q4*8];  // B[k=j][n=d]
      acc[dt] = MFMA(a,b,acc[dt]);
    }
  }
  float* po = part + (size_t)(jh*4+n)*4096*128;
  #pragma unroll
  for (int dt=0;dt<8;++dt)
    #pragma unroll
    for (int r=0;r<4;++r){
      int i = i0 + w*16 + q4*4 + r;
      int d = dt*16 + lr;
      po[(size_t)i*128 + d] = acc[dt][r];
    }
}

// ---------------- K6: combine j-halves, cast to bf16 ----------------
__global__ __launch_bounds__(256) void k_comb(const float* __restrict__ part, unsigned short* __restrict__ attn){
  size_t idx = (size_t)blockIdx.x*256 + threadIdx.x;   // 4*4096*128
  const size_t half = (size_t)4*4096*128;
  attn[idx] = f2bf(part[idx] + part[idx + half]);
}

// ---------------- K7: output projection ----------------
// y[n][c][hw] = sum_e Wo[c][e] * attn_as_[e][hw] + bo[c]   (attn flat [i*128+d] == [e][hw])
__global__ __launch_bounds__(256) void k_oproj(const unsigned short* __restrict__ attn,
                                               const unsigned short* __restrict__ Wob,
                                               const float* __restrict__ bo, float* __restrict__ y){
  constexpr int LD = 136;
  __shared__ __align__(16) unsigned short As[64*LD];   // Wo tile [c][e]
  __shared__ __align__(16) unsigned short Rt[64*LD];   // attn^T tile [hw][e]
  const int c0 = blockIdx.x*64, h0 = blockIdx.y*64, n = blockIdx.z;
  const int t = threadIdx.x, w = t>>6, lane = t&63, lr = lane&15, q4 = lane>>4;
  #pragma unroll
  for (int r=0;r<4;++r){
    int pi = t + 256*r; int cl = pi>>4, seg = pi&15;
    *(uint4*)&As[cl*LD + seg*8] = *(const uint4*)(Wob + (c0+cl)*128 + seg*8);
  }
  const unsigned short* an = attn + (size_t)n*4096*128;
  #pragma unroll
  for (int r=0;r<16;++r){                    // transpose-stage: read [e][hw] rows, write [hw][e]
    int pi = t + 256*r; int e = pi>>5, h2 = pi&31;
    unsigned u = *(const unsigned*)(an + (size_t)e*4096 + h0 + h2*2);
    Rt[(h2*2)*LD + e]   = (unsigned short)(u & 0xffffu);
    Rt[(h2*2+1)*LD + e] = (unsigned short)(u >> 16);
  }
  __syncthreads();
  ffrag acc[4] = {};
  #pragma unroll
  for (int kk=0;kk<4;++kk){
    bfrag a = *(const bfrag*)&As[(w*16+lr)*LD + kk*32 + q4*8];
    #pragma unroll
    for (int tn=0;tn<4;++tn){
      bfrag b = *(const bfrag*)&Rt[(tn*16+lr)*LD + kk*32 + q4*8];
      acc[tn] = MFMA(a,b,acc[tn]);
    }
  }
  #pragma unroll
  for (int tn=0;tn<4;++tn)
    #pragma unroll
    for (int r=0;r<4;++r){
      int c  = c0 + w*16 + q4*4 + r;
      int hw = h0 + tn*16 + lr;
      y[((size_t)n*256 + c)*4096 + hw] = acc[tn][r] + bo[c];
    }
}

extern "C" void kernel_launch(void* const* d_in, const int* in_sizes, int n_in,
                              void* d_out, int out_size, void* d_ws, size_t ws_size,
                              hipStream_t stream){
  const float* x  = (const float*)d_in[0];
  const float* Wq = (const float*)d_in[1];
  const float* bq = (const float*)d_in[2];
  const float* Wo = (const float*)d_in[3];
  const float* bo = (const float*)d_in[4];
  float* y = (float*)d_out;
  char* ws = (char*)d_ws;
  // workspace layout (bytes)
  unsigned short* qkv  = (unsigned short*)(ws + 0);          // 4*384*4096*2  = 12,582,912
  unsigned short* vtg  = (unsigned short*)(ws + 12582912);   // 4*128*4096*2  =  4,194,304
  unsigned short* attn = (unsigned short*)(ws + 16777216);   // 4*4096*128*2  =  4,194,304
  unsigned short* Wqb  = (unsigned short*)(ws + 20971520);   // 384*256*2     =    196,608
  unsigned short* Wob  = (unsigned short*)(ws + 21168128);   // 256*128*2     =     65,536
  float* mp   = (float*)(ws + 21233664);                     // 4*4*4096*4    =    262,144
  float* zp   = (float*)(ws + 21495808);                     // 4*4*4096*4    =    262,144
  float* lse  = (float*)(ws + 21757952);                     // 4*4096*4      =     65,536
  float* part = (float*)(ws + 21823488);                     // 2*4*4096*128*4= 16,777,216  (end ~38.6MB)

  k_wcast <<<dim3(384),     256, 0, stream>>>(Wq, Wo, Wqb, Wob);
  k_qkv   <<<dim3(6,64,4),  256, 0, stream>>>(x, Wqb, bq, qkv);
  k_vtrans<<<dim3(64,4),    256, 0, stream>>>(qkv, vtg);
  k_stats <<<dim3(64,4,4),  256, 0, stream>>>(qkv, mp, zp);
  k_merge <<<dim3(64),      256, 0, stream>>>(mp, zp, lse);
  k_attn  <<<dim3(64,2,4),  256, 0, stream>>>(qkv, vtg, lse, part);
  k_comb  <<<dim3(8192),    256, 0, stream>>>(part, attn);
  k_oproj <<<dim3(4,64,4),  256, 0, stream>>>(attn, Wob, bo, y);
}

// Round 3
// 252.606 us; speedup vs baseline: 1.1421x; 1.1421x over previous
//
#include <hip/hip_runtime.h>
#include <hip/hip_bf16.h>

// N=4, C=256, H=W=64 -> HW=4096, E=128, 3E=384.
// qkv flat [n][o][hw] IS [n][p][384]: q=p*384+0..127, k=+128, v=+256.
// attn flat [n][i*128+d] reinterpreted as [n][e][hw] by k_oproj (raw reshape).

typedef short bfrag __attribute__((ext_vector_type(8)));   // 8 bf16 (4 VGPRs)
typedef float ffrag __attribute__((ext_vector_type(4)));   // 4 fp32 acc
typedef unsigned short us4 __attribute__((ext_vector_type(4)));
#define MFMA(a,b,c) __builtin_amdgcn_mfma_f32_16x16x32_bf16((a),(b),(c),0,0,0)

__device__ __forceinline__ unsigned short f2bf(float f){
  union { float f; unsigned u; } v; v.f = f;
  unsigned r = v.u + 0x7fffu + ((v.u >> 16) & 1u);   // RNE
  return (unsigned short)(r >> 16);
}
__device__ __forceinline__ unsigned bfpack(float a, float b){
  return (unsigned)f2bf(a) | ((unsigned)f2bf(b) << 16);
}

// ---------------- K0: cast weights to bf16 ----------------
__global__ __launch_bounds__(256) void k_wcast(const float* __restrict__ Wq, const float* __restrict__ Wo,
                                               unsigned short* __restrict__ Wqb, unsigned short* __restrict__ Wob){
  int i = blockIdx.x*256 + threadIdx.x;
  if (i < 384*256) Wqb[i] = f2bf(Wq[i]);
  if (i < 256*128) Wob[i] = f2bf(Wo[i]);
}

// ---------------- K1: QKV projection (D[m=hw][n=o] orientation -> ushort4 stores) ----------------
__global__ __launch_bounds__(256) void k_qkv(const float* __restrict__ x, const unsigned short* __restrict__ Wqb,
                                             const float* __restrict__ bq, unsigned short* __restrict__ qkv){
  constexpr int LD = 136;
  __shared__ __align__(16) unsigned short As[64*LD];   // W tile [o][c-half]
  __shared__ __align__(16) unsigned short Bs[64*LD];   // X^T tile [hw][c-half]
  const int o0 = blockIdx.x*64, h0 = blockIdx.y*64, n = blockIdx.z;
  const int t = threadIdx.x, w = t>>6, lane = t&63, lr = lane&15, q4 = lane>>4;
  ffrag acc[4] = {};
  for (int kh = 0; kh < 2; ++kh) {
    __syncthreads();
    #pragma unroll
    for (int r=0;r<4;++r){
      int pi = t + 256*r; int o = pi>>4, seg = pi&15;
      *(uint4*)&As[o*LD + seg*8] = *(const uint4*)(Wqb + (o0+o)*256 + kh*128 + seg*8);
    }
    #pragma unroll
    for (int r=0;r<32;++r){
      int idx = t + 256*r; int cl = idx>>6, hl = idx&63;
      float v = x[(size_t)(n*256 + kh*128 + cl)*4096 + h0 + hl];
      Bs[hl*LD + cl] = f2bf(v);
    }
    __syncthreads();
    #pragma unroll
    for (int kk=0;kk<4;++kk){
      bfrag a = *(const bfrag*)&Bs[(w*16+lr)*LD + kk*32 + q4*8];   // A = x^T rows (hw)
      #pragma unroll
      for (int ot=0;ot<4;++ot){
        bfrag b = *(const bfrag*)&As[(ot*16+lr)*LD + kk*32 + q4*8]; // B = W rows (o)
        acc[ot] = MFMA(a,b,acc[ot]);                                // D[m=hw][n=o]
      }
    }
  }
  size_t base = (size_t)n*384*4096;
  #pragma unroll
  for (int ot=0;ot<4;++ot){
    int o  = o0 + ot*16 + lr;
    float bias = bq[o];
    int hw = h0 + w*16 + q4*4;
    us4 pk;
    pk.x = f2bf(acc[ot][0] + bias); pk.y = f2bf(acc[ot][1] + bias);
    pk.z = f2bf(acc[ot][2] + bias); pk.w = f2bf(acc[ot][3] + bias);
    *(us4*)(qkv + base + (size_t)o*4096 + hw) = pk;
  }
}

// ---------------- K2: global V transpose: vt[n][d][p] = v[n][p][d] ----------------
__global__ __launch_bounds__(256) void k_vtrans(const unsigned short* __restrict__ qkv, unsigned short* __restrict__ vt){
  constexpr int LD = 136;
  __shared__ __align__(16) unsigned short T[64*LD];
  const int p0 = blockIdx.x*64, n = blockIdx.y;
  const int t = threadIdx.x;
  size_t base = (size_t)n*384*4096;
  #pragma unroll
  for (int r=0;r<4;++r){
    int pi = t + 256*r; int pl = pi>>4, seg = pi&15;
    *(uint4*)&T[pl*LD + seg*8] = *(const uint4*)(qkv + base + (size_t)(p0+pl)*384 + 256 + seg*8);
  }
  __syncthreads();
  unsigned* vt32 = (unsigned*)(vt + (size_t)n*128*4096);
  #pragma unroll
  for (int r=0;r<16;++r){
    int pi = t + 256*r;            // 4096 = 128 d x 32 p-pairs
    int d = pi>>5, k = pi&31;
    unsigned lo = T[(2*k)*LD + d];
    unsigned hi = T[(2*k+1)*LD + d];
    vt32[(size_t)d*2048 + (p0>>1) + k] = lo | (hi<<16);
  }
}

// ---------------- K3: column stats, i-step 64 (16 MFMA per barrier pair) ----------------
__global__ __launch_bounds__(256) void k_stats(const unsigned short* __restrict__ qkv,
                                               float* __restrict__ mp, float* __restrict__ zp){
  constexpr int LD = 136;
  __shared__ __align__(16) unsigned short Ks[64*LD];
  __shared__ __align__(16) unsigned short Qs[64*LD];
  const int j0 = blockIdx.x*64, ic = blockIdx.y, n = blockIdx.z;
  const int t = threadIdx.x, w = t>>6, lane = t&63, lr = lane&15, q4 = lane>>4;
  size_t base = (size_t)n*384*4096;
  #pragma unroll
  for (int r=0;r<4;++r){
    int pi = t + 256*r; int jl = pi>>4, seg = pi&15;
    *(uint4*)&Ks[jl*LD + seg*8] = *(const uint4*)(qkv + base + (size_t)(j0+jl)*384 + 128 + seg*8);
  }
  float m = -3.0e38f, Z = 0.f;
  const float inv64 = 0.015625f;
  for (int ii=0; ii<16; ++ii){
    int i0 = (ic<<10) + ii*64;
    __syncthreads();
    #pragma unroll
    for (int r=0;r<4;++r){
      int pi = t + 256*r; int il = pi>>4, seg = pi&15;
      *(uint4*)&Qs[il*LD + seg*8] = *(const uint4*)(qkv + base + (size_t)(i0+il)*384 + seg*8);
    }
    __syncthreads();
    #pragma unroll
    for (int it=0; it<4; ++it){
      ffrag s = {};
      #pragma unroll
      for (int kk=0;kk<4;++kk){
        bfrag a = *(const bfrag*)&Qs[(it*16+lr)*LD + kk*32 + q4*8];     // A[m=i][k=d]
        bfrag b = *(const bfrag*)&Ks[(w*16+lr)*LD + kk*32 + q4*8];      // B[k=d][n=j]
        s = MFMA(a,b,s);
      }
      float s0=s[0]*inv64, s1=s[1]*inv64, s2=s[2]*inv64, s3=s[3]*inv64;
      float tm = fmaxf(fmaxf(s0,s1), fmaxf(s2,s3));
      tm = fmaxf(tm, __shfl_xor(tm, 16));
      tm = fmaxf(tm, __shfl_xor(tm, 32));
      float nm = fmaxf(m, tm);
      float se = __expf(s0-nm)+__expf(s1-nm)+__expf(s2-nm)+__expf(s3-nm);
      se += __shfl_xor(se, 16);
      se += __shfl_xor(se, 32);
      Z = Z*__expf(m-nm) + se;
      m = nm;
    }
  }
  if (lane < 16){
    int idx = (((n<<2)+ic)<<12) + j0 + w*16 + lane;
    mp[idx] = m; zp[idx] = Z;
  }
}

// ---------------- K4: merge partial stats -> lse[n][j] = m + log Z ----------------
__global__ __launch_bounds__(256) void k_merge(const float* __restrict__ mp, const float* __restrict__ zp,
                                               float* __restrict__ lse){
  int idx = blockIdx.x*256 + threadIdx.x;
  int n = idx>>12, j = idx&4095;
  float m = -3.0e38f, Z = 0.f;
  #pragma unroll
  for (int c=0;c<4;++c){
    int k = (((n<<2)+c)<<12) + j;
    float mc = mp[k], zc = zp[k];
    float nm = fmaxf(m, mc);
    Z = Z*__expf(m-nm) + zc*__expf(mc-nm);
    m = nm;
  }
  lse[idx] = m + __logf(Z);
}

// ---------------- K5: PV pass, S^T orientation, j-step 64 ----------------
// QK: D[m=j][n=i] = MFMA(K,Q)  -> lane holds 4 consecutive j at fixed i -> b64 P write
// PV: D[m=d][n=i] = MFMA(Vt,P) -> float4 epilogue stores
__global__ __launch_bounds__(256) void k_attn(const unsigned short* __restrict__ qkv,
                                              const unsigned short* __restrict__ vtg_all,
                                              const float* __restrict__ lse,
                                              float* __restrict__ part){
  constexpr int LDK = 136, LDV = 72, LDP = 72;
  __shared__ __align__(16) unsigned short Ks[64*LDK];    // 17408 B
  __shared__ __align__(16) unsigned short Vt[128*LDV];   // 18432 B
  __shared__ __align__(16) unsigned short Pw[4][16*LDP]; //  9216 B
  __shared__ float Ls[64];
  const int i0 = blockIdx.x*64, jh = blockIdx.y, n = blockIdx.z;
  const int t = threadIdx.x, w = t>>6, lane = t&63, lr = lane&15, q4 = lane>>4;
  size_t base = (size_t)n*384*4096;
  const unsigned short* vtg = vtg_all + (size_t)n*128*4096;
  const float* lsen = lse + (n<<12);
  bfrag qf[4];   // Q row per (w,lr); serves as B[k=d][n=i]
  {
    const unsigned short* qrow = qkv + base + (size_t)(i0 + w*16 + lr)*384;
    #pragma unroll
    for (int kk=0;kk<4;++kk) qf[kk] = *(const bfrag*)(qrow + kk*32 + q4*8);
  }
  ffrag acc[8] = {};
  const float inv64 = 0.015625f;
  for (int j0 = jh*2048; j0 < jh*2048+2048; j0 += 64){
    __syncthreads();
    #pragma unroll
    for (int r=0;r<4;++r){                    // K rows j0..j0+63
      int pi = t + 256*r; int jl = pi>>4, seg = pi&15;
      *(uint4*)&Ks[jl*LDK + seg*8] = *(const uint4*)(qkv + base + (size_t)(j0+jl)*384 + 128 + seg*8);
    }
    #pragma unroll
    for (int r=0;r<4;++r){                    // Vt[128 d][64 j]
      int pi = t + 256*r; int d = pi>>3, c = pi&7;
      *(uint4*)&Vt[d*LDV + c*8] = *(const uint4*)(vtg + (size_t)d*4096 + j0 + c*8);
    }
    if (t < 64) Ls[t] = lsen[j0 + t];
    __syncthreads();
    #pragma unroll
    for (int jt=0;jt<4;++jt){
      ffrag s = {};
      #pragma unroll
      for (int kk=0;kk<4;++kk){
        bfrag kf = *(const bfrag*)&Ks[(jt*16+lr)*LDK + kk*32 + q4*8];  // A[m=j][k=d]
        s = MFMA(kf, qf[kk], s);               // D[m=j][n=i] = S^T tile
      }
      float4 l4 = *(const float4*)&Ls[jt*16 + q4*4];
      float p0 = __expf(s[0]*inv64 - l4.x);
      float p1 = __expf(s[1]*inv64 - l4.y);
      float p2 = __expf(s[2]*inv64 - l4.z);
      float p3 = __expf(s[3]*inv64 - l4.w);
      uint2 pk; pk.x = bfpack(p0,p1); pk.y = bfpack(p2,p3);
      *(uint2*)&Pw[w][lr*LDP + jt*16 + q4*4] = pk;   // P[i=lr][j] row-contiguous, wave-private
    }
    asm volatile("" ::: "memory");             // forbid compiler reorder of Pw read above writes
    #pragma unroll
    for (int jk=0;jk<2;++jk){
      bfrag pf = *(const bfrag*)&Pw[w][lr*LDP + jk*32 + q4*8];         // B[k=j][n=i]
      #pragma unroll
      for (int dt=0;dt<8;++dt){
        bfrag af = *(const bfrag*)&Vt[(dt*16+lr)*LDV + jk*32 + q4*8];  // A[m=d][k=j]
        acc[dt] = MFMA(af, pf, acc[dt]);       // D[m=d][n=i]
      }
    }
  }
  float* po = part + (size_t)(jh*4+n)*4096*128;
  const int i = i0 + w*16 + lr;
  #pragma unroll
  for (int dt=0;dt<8;++dt){
    float4 v4 = { acc[dt][0], acc[dt][1], acc[dt][2], acc[dt][3] };
    *(float4*)(po + (size_t)i*128 + dt*16 + q4*4) = v4;
  }
}

// ---------------- K6: output projection, fused partial-combine, c-tile 128 ----------------
// y[n][c][hw] = sum_e Wo[c][e] * attn_as_[e][hw] + bo[c]; attn[e][hw] = part0+part1 at same flat idx
__global__ __launch_bounds__(256) void k_oproj(const float* __restrict__ part,
                                               const unsigned short* __restrict__ Wob,
                                               const float* __restrict__ bo, float* __restrict__ y){
  constexpr int LD = 136;
  __shared__ __align__(16) unsigned short As[128*LD];  // Wo tile [c][e]  34816 B
  __shared__ __align__(16) unsigned short Rt[64*LD];   // attn^T [hw][e]  17408 B
  const int c0 = blockIdx.x*128, h0 = blockIdx.y*64, n = blockIdx.z;
  const int t = threadIdx.x, w = t>>6, lane = t&63, lr = lane&15, q4 = lane>>4;
  const float* p0 = part + (size_t)n*4096*128;
  const float* p1 = part + (size_t)(4+n)*4096*128;
  #pragma unroll
  for (int r=0;r<8;++r){
    int pi = t + 256*r; int cl = pi>>4, seg = pi&15;
    *(uint4*)&As[cl*LD + seg*8] = *(const uint4*)(Wob + (c0+cl)*128 + seg*8);
  }
  #pragma unroll
  for (int r=0;r<16;++r){                    // read [e][hw] view of part, sum halves, transpose
    int pi = t + 256*r; int e = pi>>5, h2 = pi&31;
    size_t f = (size_t)e*4096 + h0 + h2*2;
    float a0 = p0[f]   + p1[f];
    float a1 = p0[f+1] + p1[f+1];
    Rt[(h2*2)*LD + e]   = f2bf(a0);
    Rt[(h2*2+1)*LD + e] = f2bf(a1);
  }
  __syncthreads();
  ffrag acc[8] = {};
  #pragma unroll
  for (int kk=0;kk<4;++kk){
    bfrag a = *(const bfrag*)&Rt[(w*16+lr)*LD + kk*32 + q4*8];   // A = attn^T rows (hw)
    #pragma unroll
    for (int cs=0;cs<8;++cs){
      bfrag b = *(const bfrag*)&As[(cs*16+lr)*LD + kk*32 + q4*8]; // B = Wo rows (c)
      acc[cs] = MFMA(a,b,acc[cs]);                                // D[m=hw][n=c]
    }
  }
  #pragma unroll
  for (int cs=0;cs<8;++cs){
    int c = c0 + cs*16 + lr;
    float bias = bo[c];
    float4 v4 = { acc[cs][0]+bias, acc[cs][1]+bias, acc[cs][2]+bias, acc[cs][3]+bias };
    *(float4*)(y + ((size_t)n*256 + c)*4096 + h0 + w*16 + q4*4) = v4;
  }
}

extern "C" void kernel_launch(void* const* d_in, const int* in_sizes, int n_in,
                              void* d_out, int out_size, void* d_ws, size_t ws_size,
                              hipStream_t stream){
  const float* x  = (const float*)d_in[0];
  const float* Wq = (const float*)d_in[1];
  const float* bq = (const float*)d_in[2];
  const float* Wo = (const float*)d_in[3];
  const float* bo = (const float*)d_in[4];
  float* y = (float*)d_out;
  char* ws = (char*)d_ws;
  unsigned short* qkv  = (unsigned short*)(ws + 0);          // 12,582,912
  unsigned short* vtg  = (unsigned short*)(ws + 12582912);   //  4,194,304
  // (ws+16777216 .. 20971520 unused now)
  unsigned short* Wqb  = (unsigned short*)(ws + 20971520);   //    196,608
  unsigned short* Wob  = (unsigned short*)(ws + 21168128);   //     65,536
  float* mp   = (float*)(ws + 21233664);                     //    262,144
  float* zp   = (float*)(ws + 21495808);                     //    262,144
  float* lse  = (float*)(ws + 21757952);                     //     65,536
  float* part = (float*)(ws + 21823488);                     // 16,777,216 (2 slices x 4n)

  k_wcast <<<dim3(384),     256, 0, stream>>>(Wq, Wo, Wqb, Wob);
  k_qkv   <<<dim3(6,64,4),  256, 0, stream>>>(x, Wqb, bq, qkv);
  k_vtrans<<<dim3(64,4),    256, 0, stream>>>(qkv, vtg);
  k_stats <<<dim3(64,4,4),  256, 0, stream>>>(qkv, mp, zp);
  k_merge <<<dim3(64),      256, 0, stream>>>(mp, zp, lse);
  k_attn  <<<dim3(64,2,4),  256, 0, stream>>>(qkv, vtg, lse, part);
  k_oproj <<<dim3(2,64,4),  256, 0, stream>>>(part, Wob, bo, y);
}